// Round 6
// baseline (539.347 us; speedup 1.0000x reference)
//
#include <hip/hip_runtime.h>
#include <stdint.h>

// ---------------------------------------------------------------------------
// PerceiverAttention fused pipeline (MI355X / gfx950), bf16 MFMA compute.
// b=8, f=8192, n=64, d=1024, heads=8, dim_head=64, inner=512.
// R6: big KV projection rewritten as 256x256 phase-interleaved GEMM (gemm256):
// BK=64, 512 thr / 8 waves (2Mx4N), 128 KiB dbuf LDS, 4 phases/K-tile with raw
// s_barrier (no vmcnt-drain __syncthreads), stage-at-phase0 + end-of-tile
// vmcnt(0) before the shared barrier (cross-wave gl2lds safety), setprio
// around MFMA clusters, XOR k-group swizzle on stage-source + ds_read.
// Latent K/V/Q back to its own small launch (R5 merge measured ~0 gain).
// attn: 2x256 kv sub-tiles per block w/ online rescale (R5, kept).
// ---------------------------------------------------------------------------

#define KVPAD 8448
#define NCHUNK 17

typedef __attribute__((ext_vector_type(8))) short short8;
typedef __attribute__((ext_vector_type(4))) float f32x4;

typedef __attribute__((address_space(1))) void gvoid;
typedef __attribute__((address_space(3))) void lvoid;

__device__ __forceinline__ unsigned short f2bf(float f) {
    union { float f; uint32_t u; } v; v.f = f;
    uint32_t u = v.u;
    u += 0x7fffu + ((u >> 16) & 1u);   // RNE
    return (unsigned short)(u >> 16);
}

__device__ __forceinline__ void mfma16(f32x4& c, short8 a, short8 b) {
    asm volatile("v_mfma_f32_16x16x32_bf16 %0, %1, %2, %0"
                 : "+v"(c) : "v"(a), "v"(b));
}

__device__ __forceinline__ void gl2lds16(const void* g, void* l) {
    __builtin_amdgcn_global_load_lds((gvoid*)g, (lvoid*)l, 16, 0, 0);
}

// raw barrier with compiler memory fences on both sides (no vmcnt drain)
__device__ __forceinline__ void pbar() {
    asm volatile("" ::: "memory");
    __builtin_amdgcn_s_barrier();
    asm volatile("" ::: "memory");
}
#define WAITVM(N) asm volatile("s_waitcnt vmcnt(" #N ")" ::: "memory")

// ---------------------------------------------------------------------------
// Parallel prefix scan: one block per batch, 1024 threads; thread t owns rows
// f = k*1024 + t (k=0..7). Wave shfl-scan + 16-wave LDS scan. Contention-free.
// pfx[b][f] = compacted slot if row valid; cnt[b] = total valid.
// ---------------------------------------------------------------------------
__global__ __launch_bounds__(1024) void scan_kernel(
    const int* __restrict__ mask, int* __restrict__ pfx, int* __restrict__ cnt)
{
    __shared__ int wsum[16];
    int b = blockIdx.x;
    int t = threadIdx.x, lane = t & 63, w = t >> 6;
    int c[8], tot = 0;
#pragma unroll
    for (int k = 0; k < 8; k++) {
        c[k] = (mask[b * 8192 + k * 1024 + t] == 0) ? 1 : 0;
        tot += c[k];
    }
    int run = tot;                       // wave inclusive scan
#pragma unroll
    for (int off = 1; off < 64; off <<= 1) {
        int u = __shfl_up(run, off);
        if (lane >= off) run += u;
    }
    if (lane == 63) wsum[w] = run;
    __syncthreads();
    if (t < 16) {                        // scan the 16 wave totals (lanes 0..15)
        int v = wsum[t];
#pragma unroll
        for (int off = 1; off < 16; off <<= 1) {
            int u = __shfl_up(v, off);
            if (t >= off) v += u;
        }
        wsum[t] = v;                     // inclusive
        if (t == 15) cnt[b] = v;
    }
    __syncthreads();
    int base = (w ? wsum[w - 1] : 0) + (run - tot);  // exclusive prefix
#pragma unroll
    for (int k = 0; k < 8; k++) {
        pfx[b * 8192 + k * 1024 + t] = base;
        base += c[k];
    }
}

// ---------------------------------------------------------------------------
// prep: blocks [0,16512) = LayerNorm (x compacted via pfx + latents),
// blocks [16512,17024) = the 4 weight transposes (fp32 -> bf16, RxC -> CxR).
// ---------------------------------------------------------------------------
__global__ __launch_bounds__(256) void prep_kernel(
    const float* __restrict__ X, const float* __restrict__ latents,
    const int* __restrict__ mask, const int* __restrict__ pfx,
    const float* __restrict__ gm, const float* __restrict__ bm,
    const float* __restrict__ gl, const float* __restrict__ bl,
    const float* __restrict__ Wk, const float* __restrict__ Wv,
    const float* __restrict__ Wq, const float* __restrict__ Wout,
    unsigned short* __restrict__ x_ln, unsigned short* __restrict__ lat_ln,
    unsigned short* __restrict__ WkvqT, unsigned short* __restrict__ WoutT)
{
    __shared__ float t[64][65];
    int blk = blockIdx.x;
    if (blk >= 16512) {
        // ---- weight transpose part ----
        int tt = blk - 16512;              // 0..511
        int z = tt >> 7, u = tt & 127;
        const float* S; unsigned short* D; int R, C, bx, by;
        if (z == 0)      { S = Wk;   D = WkvqT;                       R = 1024; C = 512;  by = u >> 3; bx = u & 7; }
        else if (z == 1) { S = Wv;   D = WkvqT + (size_t)512 * 1024;  R = 1024; C = 512;  by = u >> 3; bx = u & 7; }
        else if (z == 2) { S = Wq;   D = WkvqT + (size_t)1024 * 1024; R = 1024; C = 512;  by = u >> 3; bx = u & 7; }
        else             { S = Wout; D = WoutT;                       R = 512;  C = 1024; by = u >> 4; bx = u & 15; }
        int r0 = by * 64, c0 = bx * 64;
#pragma unroll
        for (int i = 0; i < 16; i++) {
            int o = i * 256 + threadIdx.x;
            int rr = o >> 6, cc = o & 63;
            t[rr][cc] = S[(size_t)(r0 + rr) * C + c0 + cc];
        }
        __syncthreads();
#pragma unroll
        for (int i = 0; i < 16; i++) {
            int o = i * 256 + threadIdx.x;
            int cl = o >> 6, rl = o & 63;
            D[(size_t)(c0 + cl) * R + r0 + rl] = f2bf(t[rl][cl]);
        }
        return;
    }
    // ---- LayerNorm part: one wave per row ----
    int lane = threadIdx.x & 63;
    int row = blk * 4 + (threadIdx.x >> 6);
    const float *src, *g, *bet;
    unsigned short* dst;
    if (row < 65536) {
        if (mask[row] != 0) return;                 // padded: skip entirely
        int b = row >> 13;
        src = X + (size_t)row * 1024;
        dst = x_ln + ((size_t)b * 8192 + pfx[row]) * 1024;
        g = gm; bet = bm;
    } else {
        int r = row - 65536;                        // 0..511
        src = latents + (size_t)r * 1024;
        dst = lat_ln + (size_t)r * 1024;
        g = gl; bet = bl;
    }
    const float4* xr = (const float4*)src;
    float4 v[4];
    float s = 0.f, s2 = 0.f;
#pragma unroll
    for (int i = 0; i < 4; i++) {
        v[i] = xr[i * 64 + lane];
        s  += v[i].x + v[i].y + v[i].z + v[i].w;
        s2 += v[i].x*v[i].x + v[i].y*v[i].y + v[i].z*v[i].z + v[i].w*v[i].w;
    }
#pragma unroll
    for (int off = 1; off < 64; off <<= 1) {
        s += __shfl_xor(s, off);
        s2 += __shfl_xor(s2, off);
    }
    float mean = s * (1.0f / 1024.0f);
    float var  = s2 * (1.0f / 1024.0f) - mean * mean;
    float rs = rsqrtf(var + 1e-5f);
    ushort4* yr = (ushort4*)dst;
    const float4* gp = (const float4*)g;
    const float4* bp = (const float4*)bet;
#pragma unroll
    for (int i = 0; i < 4; i++) {
        int c4 = i * 64 + lane;
        float4 gg = gp[c4], bb = bp[c4];
        ushort4 o;
        o.x = f2bf((v[i].x - mean) * rs * gg.x + bb.x);
        o.y = f2bf((v[i].y - mean) * rs * gg.y + bb.y);
        o.z = f2bf((v[i].z - mean) * rs * gg.z + bb.z);
        o.w = f2bf((v[i].w - mean) * rs * gg.w + bb.w);
        yr[c4] = o;
    }
}

// ---------------------------------------------------------------------------
// gemm256: the big KV projection, 256x256 tile, BK=64, 512 threads (8 waves as
// 2M x 4N, per-wave output 128x64). Double-buffered 128 KiB LDS. Per K-tile:
// 4 phases {stage@ph0 | ds_read subtile | 16 MFMA (setprio-wrapped) | s_barrier},
// end-of-tile vmcnt(0) BEFORE the barrier (cross-wave gl2lds safety), never a
// full __syncthreads drain. B-frags cached across the two M-half phases.
// A = x_ln [65536][1024] compacted rows; BT = WkvqT rows 0..1023 (Wk|Wv).
// colbase<512 -> K store (row-major bf16); else -> V^T store (ushort4).
// ---------------------------------------------------------------------------
__global__ __launch_bounds__(512, 2) void gemm256(
    const unsigned short* __restrict__ A,
    const unsigned short* __restrict__ BT,
    unsigned short* __restrict__ Ck,
    unsigned short* __restrict__ CvT,
    const int* __restrict__ cnt)
{
    __shared__ unsigned short lds[65536];   // [2 bufs][A 16384 | B 16384] u16
    int bx = blockIdx.x, by = blockIdx.y;
    // XCD-chunked bijective swizzle: 1024 blocks, 8 XCDs x 128 contiguous.
    int lid = by * 4 + bx;
    lid = (lid & 7) * 128 + (lid >> 3);
    bx = lid & 3; by = lid >> 2;
    int rowbase = by * 256;
    int colbase = bx * 256;
    int bq = by >> 5;                      // batch (8192 rows = 32 row-blocks)
    int rl0 = (by & 31) * 256;             // row within batch
    if (rl0 >= cnt[bq]) return;            // compacted early exit (pre-barrier)

    int tid = threadIdx.x;
    int lane = tid & 63;
    int wid = tid >> 6;
    int qd = lane >> 4, cc = lane & 15;
    int wm = wid >> 2, wn = wid & 3;       // wave tile: (wm*128, wn*64)

    f32x4 acc[8][4];
#pragma unroll
    for (int mf = 0; mf < 8; mf++)
#pragma unroll
        for (int nf = 0; nf < 4; nf++)
            acc[mf][nf] = (f32x4){0.f, 0.f, 0.f, 0.f};

    // staging: 4 gl2lds per operand per thread; source k-group XOR-swizzled,
    // LDS dest linear (rule: linear dest + inverse-swz source + swz read).
#define STAGE_TILE(buf, kt)                                                     \
    {                                                                           \
        int bb = (buf) * 32768;                                                 \
        _Pragma("unroll")                                                       \
        for (int i = 0; i < 4; i++) {                                           \
            int s = i * 512 + tid;                                              \
            int m = s >> 3, kc = s & 7;                                         \
            int kg = kc ^ (m & 7);                                              \
            gl2lds16(A + (size_t)(rowbase + m) * 1024 + (kt) * 64 + kg * 8,     \
                     &lds[bb + s * 8]);                                         \
        }                                                                       \
        _Pragma("unroll")                                                       \
        for (int i = 0; i < 4; i++) {                                           \
            int s = i * 512 + tid;                                              \
            int m = s >> 3, kc = s & 7;                                         \
            int kg = kc ^ (m & 7);                                              \
            gl2lds16(BT + (size_t)(colbase + m) * 1024 + (kt) * 64 + kg * 8,    \
                     &lds[bb + 16384 + s * 8]);                                 \
        }                                                                       \
    }

    STAGE_TILE(0, 0);
    WAITVM(0);
    pbar();

    int cur = 0;
#pragma unroll 1
    for (int kt = 0; kt < 16; kt++) {
        bool pf = (kt < 15);
        int ab = cur * 32768;
        int bb = ab + 16384;
        short8 bf0[4], bf1[4], af[4];

        // ---- phase 0: stage next tile; B[ks0] + A[mh0,ks0]; MFMA ----
        if (pf) STAGE_TILE(cur ^ 1, kt + 1);
#pragma unroll
        for (int nf = 0; nf < 4; nf++) {
            int n = wn * 64 + nf * 16 + cc;
            bf0[nf] = *(const short8*)&lds[bb + (n * 8 + (qd ^ (n & 7))) * 8];
        }
#pragma unroll
        for (int i = 0; i < 4; i++) {
            int m = wm * 128 + i * 16 + cc;
            af[i] = *(const short8*)&lds[ab + (m * 8 + (qd ^ (m & 7))) * 8];
        }
        __builtin_amdgcn_s_setprio(1);
#pragma unroll
        for (int i = 0; i < 4; i++)
#pragma unroll
            for (int nf = 0; nf < 4; nf++)
                mfma16(acc[i][nf], af[i], bf0[nf]);
        __builtin_amdgcn_s_setprio(0);
        pbar();

        // ---- phase 1: A[mh1,ks0]; MFMA (B cached) ----
#pragma unroll
        for (int i = 0; i < 4; i++) {
            int m = wm * 128 + (4 + i) * 16 + cc;
            af[i] = *(const short8*)&lds[ab + (m * 8 + (qd ^ (m & 7))) * 8];
        }
        __builtin_amdgcn_s_setprio(1);
#pragma unroll
        for (int i = 0; i < 4; i++)
#pragma unroll
            for (int nf = 0; nf < 4; nf++)
                mfma16(acc[4 + i][nf], af[i], bf0[nf]);
        __builtin_amdgcn_s_setprio(0);
        pbar();

        // ---- phase 2: B[ks1] + A[mh0,ks1]; MFMA ----
#pragma unroll
        for (int nf = 0; nf < 4; nf++) {
            int n = wn * 64 + nf * 16 + cc;
            bf1[nf] = *(const short8*)&lds[bb + (n * 8 + ((4 + qd) ^ (n & 7))) * 8];
        }
#pragma unroll
        for (int i = 0; i < 4; i++) {
            int m = wm * 128 + i * 16 + cc;
            af[i] = *(const short8*)&lds[ab + (m * 8 + ((4 + qd) ^ (m & 7))) * 8];
        }
        __builtin_amdgcn_s_setprio(1);
#pragma unroll
        for (int i = 0; i < 4; i++)
#pragma unroll
            for (int nf = 0; nf < 4; nf++)
                mfma16(acc[i][nf], af[i], bf1[nf]);
        __builtin_amdgcn_s_setprio(0);
        pbar();

        // ---- phase 3: A[mh1,ks1]; MFMA; vmcnt drain BEFORE barrier ----
#pragma unroll
        for (int i = 0; i < 4; i++) {
            int m = wm * 128 + (4 + i) * 16 + cc;
            af[i] = *(const short8*)&lds[ab + (m * 8 + ((4 + qd) ^ (m & 7))) * 8];
        }
        __builtin_amdgcn_s_setprio(1);
#pragma unroll
        for (int i = 0; i < 4; i++)
#pragma unroll
            for (int nf = 0; nf < 4; nf++)
                mfma16(acc[4 + i][nf], af[i], bf1[nf]);
        __builtin_amdgcn_s_setprio(0);
        if (pf) WAITVM(0);     // all waves' next-tile gl2lds done pre-barrier
        pbar();
        cur ^= 1;
    }
#undef STAGE_TILE

    // ---- epilogue: K row-major / V^T stores (block-uniform branch) ----
    bool isK = (colbase < 512);
#pragma unroll
    for (int mf = 0; mf < 8; mf++) {
        int grow = rl0 + wm * 128 + mf * 16 + qd * 4;   // 4 consecutive rows
#pragma unroll
        for (int nf = 0; nf < 4; nf++) {
            int col = colbase + wn * 64 + nf * 16 + cc;
            if (isK) {
#pragma unroll
                for (int r = 0; r < 4; r++)
                    Ck[(size_t)(bq * KVPAD + 64 + grow + r) * 512 + col] =
                        f2bf(acc[mf][nf][r]);
            } else {
                ushort4 pk;
                pk.x = f2bf(acc[mf][nf][0]);
                pk.y = f2bf(acc[mf][nf][1]);
                pk.z = f2bf(acc[mf][nf][2]);
                pk.w = f2bf(acc[mf][nf][3]);
                *(ushort4*)&CvT[((size_t)bq * 512 + (col - 512)) * KVPAD + 64 + grow] = pk;
            }
        }
    }
}

// ---------------------------------------------------------------------------
// Generic bf16 GEMM (m97 128x128 structure) — used for the small latent K/V/Q
// GEMM and the output projection. Store modes per output column:
//   col >= nq     : Q store,  Qb[(bq*64+rl+r)*512 + col-nq] * qscale (bf16)
//   col <  nsplit : row-major (bf16 Ck or fp32 Cf), row -> bq*Sstride+Ofs+rl
//   else          : transposed to CvT[(bq*512 + col-nsplit)*KVPAD + Ofs+rl]
// ---------------------------------------------------------------------------
__global__ __launch_bounds__(256) void gemm_bf16(
    const unsigned short* __restrict__ A, const unsigned short* __restrict__ BT,
    int Kd,
    unsigned short* __restrict__ Ck, float* __restrict__ Cf,
    unsigned short* __restrict__ CvT, unsigned short* __restrict__ Qb,
    int nsplit, int nq, int ldc, int P, int Sstride, int Ofs,
    float scale_const, float qscale, const float* __restrict__ scale_ptr,
    const int* __restrict__ cnt)
{
    __shared__ unsigned short a_lds[128 * 64];
    __shared__ unsigned short b_lds[128 * 64];
    int bx = blockIdx.x, by = blockIdx.y;
    size_t rowbase = (size_t)by * 128;
    size_t colbase = (size_t)bx * 128;
    if (cnt) {  // compacted A: skip row-blocks past this batch's valid count
        int bq = (int)rowbase / P, rl = (int)rowbase - bq * P;
        if (rl >= cnt[bq]) return;
    }
    int tid = threadIdx.x;
    int lane = tid & 63;
    int wave = tid >> 6;
    int wrow = (wave >> 1) * 64, wcol = (wave & 1) * 64;
    int qd = lane >> 4, cc = lane & 15;

    f32x4 acc[4][4];
#pragma unroll
    for (int mt = 0; mt < 4; mt++)
#pragma unroll
        for (int nt = 0; nt < 4; nt++)
            acc[mt][nt] = (f32x4){0.f, 0.f, 0.f, 0.f};

    int kiters = Kd >> 6;
    for (int kt = 0; kt < kiters; kt++) {
        int k0 = kt << 6;
#pragma unroll
        for (int i = 0; i < 4; i++) {
            int s = i * 256 + tid;
            int m = s >> 3, kc = s & 7;
            int kg = kc ^ (m & 7);
            gl2lds16(A + (rowbase + m) * (size_t)Kd + (k0 + kg * 8), &a_lds[s * 8]);
        }
#pragma unroll
        for (int i = 0; i < 4; i++) {
            int s = i * 256 + tid;
            int m = s >> 3, kc = s & 7;
            int kg = kc ^ (m & 7);
            gl2lds16(BT + (colbase + m) * (size_t)Kd + (k0 + kg * 8), &b_lds[s * 8]);
        }
        __syncthreads();
#pragma unroll
        for (int ks = 0; ks < 2; ks++) {
            short8 af[4], bfr[4];
            int cg = ks * 4 + qd;
#pragma unroll
            for (int mt = 0; mt < 4; mt++) {
                int m = wrow + mt * 16 + cc;
                af[mt] = *(const short8*)&a_lds[(m * 8 + (cg ^ (m & 7))) * 8];
            }
#pragma unroll
            for (int nt = 0; nt < 4; nt++) {
                int n = wcol + nt * 16 + cc;
                bfr[nt] = *(const short8*)&b_lds[(n * 8 + (cg ^ (n & 7))) * 8];
            }
#pragma unroll
            for (int mt = 0; mt < 4; mt++)
#pragma unroll
                for (int nt = 0; nt < 4; nt++)
                    mfma16(acc[mt][nt], af[mt], bfr[nt]);
        }
        __syncthreads();
    }

    float sc = scale_const;
    if (scale_ptr) sc *= *scale_ptr;
#pragma unroll
    for (int mt = 0; mt < 4; mt++) {
        int g0 = (int)rowbase + wrow + mt * 16 + qd * 4;   // 4 consecutive rows
        int bq = g0 / P, rl = g0 - bq * P;
#pragma unroll
        for (int nt = 0; nt < 4; nt++) {
            int col = (int)colbase + wcol + nt * 16 + cc;
            if (col >= nq) {
#pragma unroll
                for (int r = 0; r < 4; r++)
                    Qb[(size_t)(bq * 64 + rl + r) * 512 + (col - nq)] =
                        f2bf(acc[mt][nt][r] * qscale);
            } else if (col < nsplit) {
                int idx0 = bq * Sstride + Ofs + rl;
                if (Cf) {
#pragma unroll
                    for (int r = 0; r < 4; r++)
                        Cf[(size_t)(idx0 + r) * ldc + col] = acc[mt][nt][r] * sc;
                } else {
#pragma unroll
                    for (int r = 0; r < 4; r++)
                        Ck[(size_t)(idx0 + r) * ldc + col] = f2bf(acc[mt][nt][r] * sc);
                }
            } else {
                ushort4 pk;
                pk.x = f2bf(acc[mt][nt][0] * sc);
                pk.y = f2bf(acc[mt][nt][1] * sc);
                pk.z = f2bf(acc[mt][nt][2] * sc);
                pk.w = f2bf(acc[mt][nt][3] * sc);
                *(ushort4*)&CvT[((size_t)bq * 512 + (col - nsplit)) * KVPAD + Ofs + rl] = pk;
            }
        }
    }
}

// ---------------------------------------------------------------------------
// Attention, split-kv over compacted layout. Grid (chunk=17, h=8, b=8).
// Each block covers 512 kv slots as TWO 256-slot sub-tiles with online-softmax
// rescale between them. kv slots: [0..64) latents, [64..64+cnt[b]) features.
// ---------------------------------------------------------------------------
__global__ __launch_bounds__(256) void attn_kernel(
    const unsigned short* __restrict__ Kbuf,  // [8][8448][512]
    const unsigned short* __restrict__ Vt,    // [8][512][8448]
    const unsigned short* __restrict__ Qbuf,  // [8][64][512]
    const int* __restrict__ cnt,              // [8]
    float* __restrict__ Opart,                // [1088][64][64]
    float* __restrict__ Mpart,                // [1088][64]
    float* __restrict__ Lpart)                // [1088][64]
{
    __shared__ unsigned short P_lds[64 * 264];
    __shared__ float red_max[4][64];
    __shared__ float red_sum[4][64];
    __shared__ float mrow[64];
    __shared__ float lrow[64];
    __shared__ float frow[64];

    int chunk = blockIdx.x, h = blockIdx.y, b = blockIdx.z;
    int len = 64 + cnt[b];
    int kv0 = chunk * 512;
    if (kv0 >= len) return;

    int tid = threadIdx.x, lane = tid & 63, w = tid >> 6;
    int qd = lane >> 4, cc = lane & 15;
    int pidx = (b * 8 + h) * NCHUNK + chunk;

    // Q fragments: loaded once, reused for both sub-tiles
    short8 qf[4][2];
    const unsigned short* Qb = Qbuf + ((size_t)b * 64) * 512 + h * 64;
#pragma unroll
    for (int mt = 0; mt < 4; mt++)
#pragma unroll
        for (int ks = 0; ks < 2; ks++)
            qf[mt][ks] = *(const short8*)&Qb[(size_t)(mt * 16 + cc) * 512 + ks * 32 + qd * 8];

    f32x4 acco[4];
#pragma unroll
    for (int mt = 0; mt < 4; mt++) acco[mt] = (f32x4){0.f, 0.f, 0.f, 0.f};

    const unsigned short* Kb = Kbuf + (size_t)b * KVPAD * 512 + h * 64;
    const unsigned short* Vbase = Vt + ((size_t)b * 512 + h * 64 + w * 16 + cc) * KVPAD;

#pragma unroll 1
    for (int s = 0; s < 2; s++) {
        int kvs = kv0 + s * 256;
        if (kvs >= len) break;              // uniform per block
        int kvw = kvs + w * 64;

        // ---- QK^T for this 256-kv sub-tile ----
        f32x4 acc[4][4];
#pragma unroll
        for (int mt = 0; mt < 4; mt++)
#pragma unroll
            for (int nt = 0; nt < 4; nt++)
                acc[mt][nt] = (f32x4){0.f, 0.f, 0.f, 0.f};
#pragma unroll
        for (int nt = 0; nt < 4; nt++) {
            int kvr = kvw + nt * 16 + cc;
#pragma unroll
            for (int ks = 0; ks < 2; ks++) {
                short8 kf = *(const short8*)&Kb[(size_t)kvr * 512 + ks * 32 + qd * 8];
#pragma unroll
                for (int mt = 0; mt < 4; mt++)
                    mfma16(acc[mt][nt], qf[mt][ks], kf);
            }
        }
        // mask invalid slots (>= len)
#pragma unroll
        for (int nt = 0; nt < 4; nt++) {
            int kv = kvw + nt * 16 + cc;
            if (kv >= len) {
#pragma unroll
                for (int mt = 0; mt < 4; mt++)
#pragma unroll
                    for (int r = 0; r < 4; r++) acc[mt][nt][r] = -1e30f;
            }
        }
        // ---- sub-tile max reduce ----
        float vmax[4][4];
#pragma unroll
        for (int mt = 0; mt < 4; mt++)
#pragma unroll
            for (int r = 0; r < 4; r++)
                vmax[mt][r] = fmaxf(fmaxf(acc[mt][0][r], acc[mt][1][r]),
                                    fmaxf(acc[mt][2][r], acc[mt][3][r]));
#pragma unroll
        for (int off = 1; off < 16; off <<= 1)
#pragma unroll
            for (int mt = 0; mt < 4; mt++)
#pragma unroll
                for (int r = 0; r < 4; r++)
                    vmax[mt][r] = fmaxf(vmax[mt][r], __shfl_xor(vmax[mt][r], off));
        if (cc == 0) {
#pragma unroll
            for (int mt = 0; mt < 4; mt++)
#pragma unroll
                for (int r = 0; r < 4; r++)
                    red_max[w][mt * 16 + qd * 4 + r] = vmax[mt][r];
        }
        __syncthreads();                                    // B1
        if (tid < 64) {
            float tmax = fmaxf(fmaxf(red_max[0][tid], red_max[1][tid]),
                               fmaxf(red_max[2][tid], red_max[3][tid]));
            if (s == 0) {
                mrow[tid] = tmax;
            } else {
                float mo = mrow[tid];
                float mn = fmaxf(mo, tmax);
                frow[tid] = __expf(mo - mn);
                mrow[tid] = mn;
            }
        }
        __syncthreads();                                    // B2
        // ---- P = exp(S - m), row sums ----
        float vsum[4][4];
#pragma unroll
        for (int mt = 0; mt < 4; mt++)
#pragma unroll
            for (int r = 0; r < 4; r++) {
                int row = mt * 16 + qd * 4 + r;
                float m = mrow[row];
                float ssum = 0.f;
#pragma unroll
                for (int nt = 0; nt < 4; nt++) {
                    float p = __expf(acc[mt][nt][r] - m);
                    ssum += p;
                    P_lds[row * 264 + w * 64 + nt * 16 + cc] = f2bf(p);
                }
                vsum[mt][r] = ssum;
            }
#pragma unroll
        for (int off = 1; off < 16; off <<= 1)
#pragma unroll
            for (int mt = 0; mt < 4; mt++)
#pragma unroll
                for (int r = 0; r < 4; r++)
                    vsum[mt][r] += __shfl_xor(vsum[mt][r], off);
        if (cc == 0) {
#pragma unroll
            for (int mt = 0; mt < 4; mt++)
#pragma unroll
                for (int r = 0; r < 4; r++)
                    red_sum[w][mt * 16 + qd * 4 + r] = vsum[mt][r];
        }
        __syncthreads();                                    // B3
        if (tid < 64) {
            float snew = red_sum[0][tid] + red_sum[1][tid] +
                         red_sum[2][tid] + red_sum[3][tid];
            lrow[tid] = (s == 0) ? snew : lrow[tid] * frow[tid] + snew;
        }
        // rescale accumulated O by exp(m_old - m_new) (frow stable since B2)
        if (s > 0) {
#pragma unroll
            for (int mt = 0; mt < 4; mt++)
#pragma unroll
                for (int r = 0; r < 4; r++)
                    acco[mt][r] *= frow[mt * 16 + qd * 4 + r];
        }
        // ---- PV accumulate (P_lds stable since B3; next overwrite is after
        // next iteration's B2, which all waves reach only post-PV) ----
        const unsigned short* Vb = Vbase + kvs;
#pragma unroll
        for (int ks = 0; ks < 8; ks++) {
            short8 vf = *(const short8*)&Vb[ks * 32 + qd * 8];
#pragma unroll
            for (int mt = 0; mt < 4; mt++) {
                short8 pf = *(const short8*)&P_lds[(size_t)(mt * 16 + cc) * 264 + ks * 32 + qd * 8];
                mfma16(acco[mt], pf, vf);
            }
        }
    }

    if (tid < 64) {
        Mpart[(size_t)pidx * 64 + tid] = mrow[tid];
        Lpart[(size_t)pidx * 64 + tid] = lrow[tid];
    }
    float* Ob = Opart + (size_t)pidx * 4096;
#pragma unroll
    for (int mt = 0; mt < 4; mt++)
#pragma unroll
        for (int r = 0; r < 4; r++)
            Ob[(size_t)(mt * 16 + qd * 4 + r) * 64 + w * 16 + cc] = acco[mt][r];
}

// ---------------------------------------------------------------------------
// Combine split-kv partials over ACTIVE chunks only (512-kv chunks).
// ---------------------------------------------------------------------------
__global__ __launch_bounds__(256) void combine_kernel(
    const float* __restrict__ Opart, const float* __restrict__ Mpart,
    const float* __restrict__ Lpart, const int* __restrict__ cnt,
    unsigned short* __restrict__ AttnOut)
{
    __shared__ float wls[NCHUNK][16];
    __shared__ float invl[16];
    int bh = blockIdx.x >> 2, qg = blockIdx.x & 3;
    int b = bh >> 3, h = bh & 7;
    int pbase = bh * NCHUNK;
    int nact = (64 + cnt[b] + 511) >> 9;   // active 512-kv chunks for this batch
    int tid = threadIdx.x;
    if (tid < 16) {
        int q = qg * 16 + tid;
        float M = -3.0e38f;
        for (int cn = 0; cn < nact; cn++)
            M = fmaxf(M, Mpart[(size_t)(pbase + cn) * 64 + q]);
        float l = 0.f;
        for (int cn = 0; cn < nact; cn++) {
            float wc = __expf(Mpart[(size_t)(pbase + cn) * 64 + q] - M);
            wls[cn][tid] = wc;
            l += wc * Lpart[(size_t)(pbase + cn) * 64 + q];
        }
        invl[tid] = 1.0f / l;
    }
    __syncthreads();
    int ql = tid >> 4, d4 = (tid & 15) * 4;
    int q = qg * 16 + ql;
    float ax = 0.f, ay = 0.f, az = 0.f, aw = 0.f;
    for (int cn = 0; cn < nact; cn++) {
        float wc = wls[cn][ql];
        float4 o = *(const float4*)&Opart[((size_t)(pbase + cn) * 64 + q) * 64 + d4];
        ax += wc * o.x; ay += wc * o.y; az += wc * o.z; aw += wc * o.w;
    }
    float iv = invl[ql];
    ushort4 pk;
    pk.x = f2bf(ax * iv); pk.y = f2bf(ay * iv);
    pk.z = f2bf(az * iv); pk.w = f2bf(aw * iv);
    *(ushort4*)&AttnOut[((size_t)b * 64 + q) * 512 + h * 64 + d4] = pk;
}

// ---------------------------------------------------------------------------
// Workspace layout (bytes). x_ln (0..134M) is dead after the big GEMM and is
// reused for attention partials. Qbuf/AttnOut live OUTSIDE the x_ln region.
// ---------------------------------------------------------------------------
#define OPART_OFF    ((size_t)0)            // 1088*64*64*4 = 17,825,792
#define MPART_OFF    ((size_t)34603008)     // 1088*64*4    =    278,528
#define LPART_OFF    ((size_t)35143680)
#define XLN_OFF      ((size_t)0)            // 8*8192*1024*2 = 134,217,728
#define LATLN_OFF    ((size_t)134217728)    // 512*1024*2
#define KBUF_OFF     ((size_t)135266304)    // 8*8448*512*2 = 69,206,016
#define VT_OFF       ((size_t)204472320)    // 8*512*8448*2
#define WKVQT_OFF    ((size_t)273678336)    // 1536*1024*2 = 3,145,728
#define WOUTT_OFF    ((size_t)276824064)    // 1024*512*2  = 1,048,576
#define PFX_OFF      ((size_t)277872640)    // 8*8192*4 = 262,144
#define CNT_OFF      ((size_t)278134784)    // 8*4
#define QBUF_OFF     ((size_t)278134912)    // 512*512*2 = 524,288 (outside x_ln)
#define ATTNOUT_OFF  ((size_t)278659200)    // 512*512*2 ; end 279,183,488

extern "C" void kernel_launch(void* const* d_in, const int* in_sizes, int n_in,
                              void* d_out, int out_size, void* d_ws, size_t ws_size,
                              hipStream_t stream) {
    const float* x       = (const float*)d_in[0];
    const float* latents = (const float*)d_in[1];
    const int*   mask    = (const int*)d_in[2];
    const float* kv_gate = (const float*)d_in[3];
    const float* gm      = (const float*)d_in[4];
    const float* bm      = (const float*)d_in[5];
    const float* gl      = (const float*)d_in[6];
    const float* bl      = (const float*)d_in[7];
    const float* Wq      = (const float*)d_in[8];
    const float* Wk      = (const float*)d_in[9];
    const float* Wv      = (const float*)d_in[10];
    const float* Wout    = (const float*)d_in[11];
    float* out = (float*)d_out;

    char* ws = (char*)d_ws;
    float* Opart = (float*)(ws + OPART_OFF);
    float* Mpart = (float*)(ws + MPART_OFF);
    float* Lpart = (float*)(ws + LPART_OFF);
    unsigned short* Qbuf    = (unsigned short*)(ws + QBUF_OFF);
    unsigned short* AttnOut = (unsigned short*)(ws + ATTNOUT_OFF);
    unsigned short* x_ln    = (unsigned short*)(ws + XLN_OFF);
    unsigned short* lat_ln  = (unsigned short*)(ws + LATLN_OFF);
    unsigned short* Kbuf    = (unsigned short*)(ws + KBUF_OFF);
    unsigned short* Vt      = (unsigned short*)(ws + VT_OFF);
    unsigned short* WkvqT   = (unsigned short*)(ws + WKVQT_OFF);
    unsigned short* WoutT   = (unsigned short*)(ws + WOUTT_OFF);
    int* pfx = (int*)(ws + PFX_OFF);
    int* cnt = (int*)(ws + CNT_OFF);

    // 1) Parallel mask prefix scan (one block per batch, contention-free)
    scan_kernel<<<8, 1024, 0, stream>>>(mask, pfx, cnt);

    // 2) prep: LN (compacted x via pfx + latents) + weight transposes
    prep_kernel<<<17024, 256, 0, stream>>>(
        x, latents, mask, pfx, gm, bm, gl, bl, Wk, Wv, Wq, Wout,
        x_ln, lat_ln, WkvqT, WoutT);

    // 3) Latent K/V/Q (K,V x kv_gate -> slots 0..63; Q x 0.125) — small GEMM
    gemm_bf16<<<dim3(12, 4), 256, 0, stream>>>(
        lat_ln, WkvqT, 1024, Kbuf, nullptr, Vt, Qbuf,
        512, 1024, 512, 64, KVPAD, 0, 1.0f, 0.125f, kv_gate, nullptr);

    // 4) Big KV projection (compacted rows): 256^2 phase-interleaved GEMM
    gemm256<<<dim3(4, 256), 512, 0, stream>>>(x_ln, WkvqT, Kbuf, Vt, cnt);

    // 5) Split-kv attention partials (512-kv chunks, 2 sub-tiles per block)
    attn_kernel<<<dim3(NCHUNK, 8, 8), 256, 0, stream>>>(
        Kbuf, Vt, Qbuf, cnt, Opart, Mpart, Lpart);

    // 6) Combine partials -> AttnOut bf16 [512][512]
    combine_kernel<<<256, 256, 0, stream>>>(Opart, Mpart, Lpart, cnt, AttnOut);

    // 7) Output projection: AttnOut(512x512) @ Wout -> out fp32 (8,64,1024)
    gemm_bf16<<<dim3(8, 4), 256, 0, stream>>>(
        AttnOut, WoutT, 512, nullptr, out, nullptr, nullptr,
        1 << 30, 1 << 30, 1024, 64, 64, 0, 1.0f, 0.f, nullptr, nullptr);
}

// Round 8
// 534.919 us; speedup vs baseline: 1.0083x; 1.0083x over previous
//
#include <hip/hip_runtime.h>
#include <stdint.h>

// ---------------------------------------------------------------------------
// PerceiverAttention fused pipeline (MI355X / gfx950), bf16 MFMA compute.
// b=8, f=8192, n=64, d=1024, heads=8, dim_head=64, inner=512.
// R7: gemm256 K-loop rewritten as a TRUE counted-vmcnt 8-phase schedule
// (R6's stage-all+vmcnt(0)-per-tile was the documented-bad "coarse split +
// drain-0" config: 539us vs 511us). Per iteration (2 K-tiles): 8 phases, one
// half-tile stage per phase, vmcnt(4) only at phases 4/8 (in-order retirement
// covers the full needed tile; 6-phase stage->consume lead > HBM latency),
// A/B fragments register-cached across phases. Everything else (swizzles,
// epilogue, attn 2x256 online-rescale, NCHUNK 17) unchanged from R6.
// Revert anchor if this regresses: R2-submission (128^2 GEMM, 511.5us).
// ---------------------------------------------------------------------------

#define KVPAD 8448
#define NCHUNK 17

typedef __attribute__((ext_vector_type(8))) short short8;
typedef __attribute__((ext_vector_type(4))) float f32x4;

typedef __attribute__((address_space(1))) void gvoid;
typedef __attribute__((address_space(3))) void lvoid;

__device__ __forceinline__ unsigned short f2bf(float f) {
    union { float f; uint32_t u; } v; v.f = f;
    uint32_t u = v.u;
    u += 0x7fffu + ((u >> 16) & 1u);   // RNE
    return (unsigned short)(u >> 16);
}

__device__ __forceinline__ void mfma16(f32x4& c, short8 a, short8 b) {
    asm volatile("v_mfma_f32_16x16x32_bf16 %0, %1, %2, %0"
                 : "+v"(c) : "v"(a), "v"(b));
}

__device__ __forceinline__ void gl2lds16(const void* g, void* l) {
    __builtin_amdgcn_global_load_lds((gvoid*)g, (lvoid*)l, 16, 0, 0);
}

// raw barrier with compiler memory fences on both sides (no vmcnt drain)
__device__ __forceinline__ void pbar() {
    asm volatile("" ::: "memory");
    __builtin_amdgcn_s_barrier();
    asm volatile("" ::: "memory");
}
#define WAITVM(N) asm volatile("s_waitcnt vmcnt(" #N ")" ::: "memory")

// ---------------------------------------------------------------------------
// Parallel prefix scan: one block per batch, 1024 threads; thread t owns rows
// f = k*1024 + t (k=0..7). Wave shfl-scan + 16-wave LDS scan. Contention-free.
// pfx[b][f] = compacted slot if row valid; cnt[b] = total valid.
// ---------------------------------------------------------------------------
__global__ __launch_bounds__(1024) void scan_kernel(
    const int* __restrict__ mask, int* __restrict__ pfx, int* __restrict__ cnt)
{
    __shared__ int wsum[16];
    int b = blockIdx.x;
    int t = threadIdx.x, lane = t & 63, w = t >> 6;
    int c[8], tot = 0;
#pragma unroll
    for (int k = 0; k < 8; k++) {
        c[k] = (mask[b * 8192 + k * 1024 + t] == 0) ? 1 : 0;
        tot += c[k];
    }
    int run = tot;                       // wave inclusive scan
#pragma unroll
    for (int off = 1; off < 64; off <<= 1) {
        int u = __shfl_up(run, off);
        if (lane >= off) run += u;
    }
    if (lane == 63) wsum[w] = run;
    __syncthreads();
    if (t < 16) {                        // scan the 16 wave totals (lanes 0..15)
        int v = wsum[t];
#pragma unroll
        for (int off = 1; off < 16; off <<= 1) {
            int u = __shfl_up(v, off);
            if (t >= off) v += u;
        }
        wsum[t] = v;                     // inclusive
        if (t == 15) cnt[b] = v;
    }
    __syncthreads();
    int base = (w ? wsum[w - 1] : 0) + (run - tot);  // exclusive prefix
#pragma unroll
    for (int k = 0; k < 8; k++) {
        pfx[b * 8192 + k * 1024 + t] = base;
        base += c[k];
    }
}

// ---------------------------------------------------------------------------
// prep: blocks [0,16512) = LayerNorm (x compacted via pfx + latents),
// blocks [16512,17024) = the 4 weight transposes (fp32 -> bf16, RxC -> CxR).
// ---------------------------------------------------------------------------
__global__ __launch_bounds__(256) void prep_kernel(
    const float* __restrict__ X, const float* __restrict__ latents,
    const int* __restrict__ mask, const int* __restrict__ pfx,
    const float* __restrict__ gm, const float* __restrict__ bm,
    const float* __restrict__ gl, const float* __restrict__ bl,
    const float* __restrict__ Wk, const float* __restrict__ Wv,
    const float* __restrict__ Wq, const float* __restrict__ Wout,
    unsigned short* __restrict__ x_ln, unsigned short* __restrict__ lat_ln,
    unsigned short* __restrict__ WkvqT, unsigned short* __restrict__ WoutT)
{
    __shared__ float t[64][65];
    int blk = blockIdx.x;
    if (blk >= 16512) {
        // ---- weight transpose part ----
        int tt = blk - 16512;              // 0..511
        int z = tt >> 7, u = tt & 127;
        const float* S; unsigned short* D; int R, C, bx, by;
        if (z == 0)      { S = Wk;   D = WkvqT;                       R = 1024; C = 512;  by = u >> 3; bx = u & 7; }
        else if (z == 1) { S = Wv;   D = WkvqT + (size_t)512 * 1024;  R = 1024; C = 512;  by = u >> 3; bx = u & 7; }
        else if (z == 2) { S = Wq;   D = WkvqT + (size_t)1024 * 1024; R = 1024; C = 512;  by = u >> 3; bx = u & 7; }
        else             { S = Wout; D = WoutT;                       R = 512;  C = 1024; by = u >> 4; bx = u & 15; }
        int r0 = by * 64, c0 = bx * 64;
#pragma unroll
        for (int i = 0; i < 16; i++) {
            int o = i * 256 + threadIdx.x;
            int rr = o >> 6, cc = o & 63;
            t[rr][cc] = S[(size_t)(r0 + rr) * C + c0 + cc];
        }
        __syncthreads();
#pragma unroll
        for (int i = 0; i < 16; i++) {
            int o = i * 256 + threadIdx.x;
            int cl = o >> 6, rl = o & 63;
            D[(size_t)(c0 + cl) * R + r0 + rl] = f2bf(t[rl][cl]);
        }
        return;
    }
    // ---- LayerNorm part: one wave per row ----
    int lane = threadIdx.x & 63;
    int row = blk * 4 + (threadIdx.x >> 6);
    const float *src, *g, *bet;
    unsigned short* dst;
    if (row < 65536) {
        if (mask[row] != 0) return;                 // padded: skip entirely
        int b = row >> 13;
        src = X + (size_t)row * 1024;
        dst = x_ln + ((size_t)b * 8192 + pfx[row]) * 1024;
        g = gm; bet = bm;
    } else {
        int r = row - 65536;                        // 0..511
        src = latents + (size_t)r * 1024;
        dst = lat_ln + (size_t)r * 1024;
        g = gl; bet = bl;
    }
    const float4* xr = (const float4*)src;
    float4 v[4];
    float s = 0.f, s2 = 0.f;
#pragma unroll
    for (int i = 0; i < 4; i++) {
        v[i] = xr[i * 64 + lane];
        s  += v[i].x + v[i].y + v[i].z + v[i].w;
        s2 += v[i].x*v[i].x + v[i].y*v[i].y + v[i].z*v[i].z + v[i].w*v[i].w;
    }
#pragma unroll
    for (int off = 1; off < 64; off <<= 1) {
        s += __shfl_xor(s, off);
        s2 += __shfl_xor(s2, off);
    }
    float mean = s * (1.0f / 1024.0f);
    float var  = s2 * (1.0f / 1024.0f) - mean * mean;
    float rs = rsqrtf(var + 1e-5f);
    ushort4* yr = (ushort4*)dst;
    const float4* gp = (const float4*)g;
    const float4* bp = (const float4*)bet;
#pragma unroll
    for (int i = 0; i < 4; i++) {
        int c4 = i * 64 + lane;
        float4 gg = gp[c4], bb = bp[c4];
        ushort4 o;
        o.x = f2bf((v[i].x - mean) * rs * gg.x + bb.x);
        o.y = f2bf((v[i].y - mean) * rs * gg.y + bb.y);
        o.z = f2bf((v[i].z - mean) * rs * gg.z + bb.z);
        o.w = f2bf((v[i].w - mean) * rs * gg.w + bb.w);
        yr[c4] = o;
    }
}

// ---------------------------------------------------------------------------
// gemm256: big KV projection, 256x256 tile, BK=64, 512 thr / 8 waves (2Mx4N,
// per-wave 128x64). LDS: dbuf by K-tile parity (even->par0, odd->par1),
// each par = A 32KiB | B 32KiB. 8-phase counted-vmcnt schedule per iteration
// (2 K-tiles): phase = {ds_read subtile | stage ONE half-tile (2 gl2lds/thr) |
// barrier | 16 MFMA setprio-wrapped | barrier}. vmcnt(4) only at phases 4/8
// (final iter: p4 uses vmcnt(0) since p3/p4 stages are guarded off).
// Stage order (slot-lifetime-derived): p1,p2=A(odd tile); p3..p6=B0,B1,A0,A1
// (next even); p7,p8=B(next odd). Stage->consume lead ~6 phases > HBM latency.
// colbase<512 -> K store (row-major bf16); else -> V^T store (ushort4).
// ---------------------------------------------------------------------------
__global__ __launch_bounds__(512, 2) void gemm256(
    const unsigned short* __restrict__ A,
    const unsigned short* __restrict__ BT,
    unsigned short* __restrict__ Ck,
    unsigned short* __restrict__ CvT,
    const int* __restrict__ cnt)
{
    __shared__ unsigned short lds[65536];   // [par][A 16384 | B 16384] u16
    int bx = blockIdx.x, by = blockIdx.y;
    // XCD-chunked bijective swizzle: 1024 blocks, 8 XCDs x 128 contiguous.
    int lid = by * 4 + bx;
    lid = (lid & 7) * 128 + (lid >> 3);
    bx = lid & 3; by = lid >> 2;
    int rowbase = by * 256;
    int colbase = bx * 256;
    int bq = by >> 5;                      // batch (8192 rows = 32 row-blocks)
    int rl0 = (by & 31) * 256;             // row within batch
    if (rl0 >= cnt[bq]) return;            // compacted early exit (pre-barrier)

    int tid = threadIdx.x;
    int lane = tid & 63;
    int wid = tid >> 6;
    int qd = lane >> 4, cc = lane & 15;
    int wm = wid >> 2, wn = wid & 3;       // wave tile: (wm*128, wn*64)

    f32x4 acc[8][4];
#pragma unroll
    for (int mf = 0; mf < 8; mf++)
#pragma unroll
        for (int nf = 0; nf < 4; nf++)
            acc[mf][nf] = (f32x4){0.f, 0.f, 0.f, 0.f};

    // stage one half-tile (128 rows x 64 cols) of A (isB=0) or B (isB=1),
    // half h, K-tile kt, into parity buffer par. 2 gl2lds x 16B per thread.
    // source k-group XOR-swizzled, LDS dest linear (both-sides involution).
#define STAGE_HALF(par, isB, h, kt)                                            \
    if ((kt) < 16) {                                                           \
        const unsigned short* srcb = (isB) ? BT : A;                           \
        int rb = (isB) ? colbase : rowbase;                                    \
        _Pragma("unroll")                                                      \
        for (int i = 0; i < 2; i++) {                                          \
            int s = i * 512 + tid;                                             \
            int ml = s >> 3, kc = s & 7;                                       \
            int kg = kc ^ (ml & 7);                                            \
            gl2lds16(srcb + (size_t)(rb + (h) * 128 + ml) * 1024               \
                          + (kt) * 64 + kg * 8,                                \
                     &lds[(par) * 32768 + (isB) * 16384 + (h) * 8192 + s * 8]);\
        }                                                                      \
    }

    // read A frags for M-half mh (4 mf x 2 kslices = 8 ds_read_b128)
#define RD_A(par, mh)                                                          \
    _Pragma("unroll")                                                          \
    for (int i = 0; i < 4; i++) {                                              \
        int m = wm * 128 + ((mh) * 4 + i) * 16 + cc;                           \
        _Pragma("unroll")                                                      \
        for (int ks = 0; ks < 2; ks++) {                                       \
            int cg = ks * 4 + qd;                                              \
            afr[i][ks] = *(const short8*)&lds[(par) * 32768 +                  \
                              (m * 8 + (cg ^ (m & 7))) * 8];                   \
        }                                                                      \
    }

    // read B frags for N-frag-pair nfp (2 nf x 2 kslices = 4 ds_read_b128)
#define RD_B(par, nfp, dst)                                                    \
    _Pragma("unroll")                                                          \
    for (int j = 0; j < 2; j++) {                                              \
        int n = wn * 64 + ((nfp) * 2 + j) * 16 + cc;                           \
        _Pragma("unroll")                                                      \
        for (int ks = 0; ks < 2; ks++) {                                       \
            int cg = ks * 4 + qd;                                              \
            dst[j][ks] = *(const short8*)&lds[(par) * 32768 + 16384 +          \
                              (n * 8 + (cg ^ (n & 7))) * 8];                   \
        }                                                                      \
    }

    // 16 MFMA: C-quadrant (mh, nfp) over full K=64 (both k-slices)
#define DO_MFMA(mh, nfp, bsrc)                                                 \
    __builtin_amdgcn_s_setprio(1);                                             \
    _Pragma("unroll")                                                          \
    for (int i = 0; i < 4; i++)                                                \
        _Pragma("unroll")                                                      \
        for (int j = 0; j < 2; j++)                                            \
            _Pragma("unroll")                                                  \
            for (int ks = 0; ks < 2; ks++)                                     \
                mfma16(acc[(mh) * 4 + i][(nfp) * 2 + j],                       \
                       afr[i][ks], bsrc[j][ks]);                               \
    __builtin_amdgcn_s_setprio(0);

    // prologue: tile0 full (par0) + tile1 B-halves (par1); A of tile1 is
    // staged at iter0 p1,p2. vmcnt(4): tile0's 8 loads retired, tile1-B's 4
    // may remain in flight (covered by iter0's p4 wait).
    STAGE_HALF(0, 0, 0, 0); STAGE_HALF(0, 0, 1, 0);
    STAGE_HALF(0, 1, 0, 0); STAGE_HALF(0, 1, 1, 0);
    STAGE_HALF(1, 1, 0, 1); STAGE_HALF(1, 1, 1, 1);
    WAITVM(4);
    pbar();

    short8 afr[4][2], bfr0[2][2], bfr1[2][2];
#pragma unroll 1
    for (int it = 0; it < 8; it++) {
        int t1k = 2 * it + 1, t2k = 2 * it + 2, t3k = 2 * it + 3;

        // ---- p1: par0 (mh0,nfp0); stage A0(odd tile t1k -> par1) ----
        RD_A(0, 0); RD_B(0, 0, bfr0);
        STAGE_HALF(1, 0, 0, t1k);
        pbar();
        DO_MFMA(0, 0, bfr0);
        pbar();
        // ---- p2: par0 (mh0,nfp1); stage A1(t1k -> par1) ----
        RD_B(0, 1, bfr1);
        STAGE_HALF(1, 0, 1, t1k);
        pbar();
        DO_MFMA(0, 1, bfr1);
        pbar();
        // ---- p3: par0 (mh1,nfp0); stage B0(t2k -> par0) [B-par0 dead] ----
        RD_A(0, 1);
        STAGE_HALF(0, 1, 0, t2k);
        pbar();
        DO_MFMA(1, 0, bfr0);
        pbar();
        // ---- p4: par0 (mh1,nfp1); stage B1(t2k -> par0); counted wait ----
        STAGE_HALF(0, 1, 1, t2k);
        pbar();
        DO_MFMA(1, 1, bfr1);
        // retire everything except p3,p4 stages -> odd tile (B@prev p7,p8 +
        // A@p1,p2) fully landed. Final iter: p3,p4 guarded off -> drain to 0.
        if (it < 7) { WAITVM(4); } else { WAITVM(0); }
        pbar();
        // ---- p5: par1 (mh0,nfp0); stage A0(t2k -> par0) [A-par0 dead] ----
        RD_A(1, 0); RD_B(1, 0, bfr0);
        STAGE_HALF(0, 0, 0, t2k);
        pbar();
        DO_MFMA(0, 0, bfr0);
        pbar();
        // ---- p6: par1 (mh0,nfp1); stage A1(t2k -> par0) ----
        RD_B(1, 1, bfr1);
        STAGE_HALF(0, 0, 1, t2k);
        pbar();
        DO_MFMA(0, 1, bfr1);
        pbar();
        // ---- p7: par1 (mh1,nfp0); stage B0(t3k -> par1) [B-par1 dead] ----
        RD_A(1, 1);
        STAGE_HALF(1, 1, 0, t3k);
        pbar();
        DO_MFMA(1, 0, bfr0);
        pbar();
        // ---- p8: par1 (mh1,nfp1); stage B1(t3k -> par1); counted wait ----
        STAGE_HALF(1, 1, 1, t3k);
        pbar();
        DO_MFMA(1, 1, bfr1);
        WAITVM(4);   // retire p3..p6 stages -> next even tile fully landed
        pbar();
    }
#undef STAGE_HALF
#undef RD_A
#undef RD_B
#undef DO_MFMA

    // ---- epilogue: K row-major / V^T stores (block-uniform branch) ----
    bool isK = (colbase < 512);
#pragma unroll
    for (int mf = 0; mf < 8; mf++) {
        int grow = rl0 + wm * 128 + mf * 16 + qd * 4;   // 4 consecutive rows
#pragma unroll
        for (int nf = 0; nf < 4; nf++) {
            int col = colbase + wn * 64 + nf * 16 + cc;
            if (isK) {
#pragma unroll
                for (int r = 0; r < 4; r++)
                    Ck[(size_t)(bq * KVPAD + 64 + grow + r) * 512 + col] =
                        f2bf(acc[mf][nf][r]);
            } else {
                ushort4 pk;
                pk.x = f2bf(acc[mf][nf][0]);
                pk.y = f2bf(acc[mf][nf][1]);
                pk.z = f2bf(acc[mf][nf][2]);
                pk.w = f2bf(acc[mf][nf][3]);
                *(ushort4*)&CvT[((size_t)bq * 512 + (col - 512)) * KVPAD + 64 + grow] = pk;
            }
        }
    }
}

// ---------------------------------------------------------------------------
// Generic bf16 GEMM (m97 128x128 structure) — used for the small latent K/V/Q
// GEMM and the output projection. Store modes per output column:
//   col >= nq     : Q store,  Qb[(bq*64+rl+r)*512 + col-nq] * qscale (bf16)
//   col <  nsplit : row-major (bf16 Ck or fp32 Cf), row -> bq*Sstride+Ofs+rl
//   else          : transposed to CvT[(bq*512 + col-nsplit)*KVPAD + Ofs+rl]
// ---------------------------------------------------------------------------
__global__ __launch_bounds__(256) void gemm_bf16(
    const unsigned short* __restrict__ A, const unsigned short* __restrict__ BT,
    int Kd,
    unsigned short* __restrict__ Ck, float* __restrict__ Cf,
    unsigned short* __restrict__ CvT, unsigned short* __restrict__ Qb,
    int nsplit, int nq, int ldc, int P, int Sstride, int Ofs,
    float scale_const, float qscale, const float* __restrict__ scale_ptr,
    const int* __restrict__ cnt)
{
    __shared__ unsigned short a_lds[128 * 64];
    __shared__ unsigned short b_lds[128 * 64];
    int bx = blockIdx.x, by = blockIdx.y;
    size_t rowbase = (size_t)by * 128;
    size_t colbase = (size_t)bx * 128;
    if (cnt) {  // compacted A: skip row-blocks past this batch's valid count
        int bq = (int)rowbase / P, rl = (int)rowbase - bq * P;
        if (rl >= cnt[bq]) return;
    }
    int tid = threadIdx.x;
    int lane = tid & 63;
    int wave = tid >> 6;
    int wrow = (wave >> 1) * 64, wcol = (wave & 1) * 64;
    int qd = lane >> 4, cc = lane & 15;

    f32x4 acc[4][4];
#pragma unroll
    for (int mt = 0; mt < 4; mt++)
#pragma unroll
        for (int nt = 0; nt < 4; nt++)
            acc[mt][nt] = (f32x4){0.f, 0.f, 0.f, 0.f};

    int kiters = Kd >> 6;
    for (int kt = 0; kt < kiters; kt++) {
        int k0 = kt << 6;
#pragma unroll
        for (int i = 0; i < 4; i++) {
            int s = i * 256 + tid;
            int m = s >> 3, kc = s & 7;
            int kg = kc ^ (m & 7);
            gl2lds16(A + (rowbase + m) * (size_t)Kd + (k0 + kg * 8), &a_lds[s * 8]);
        }
#pragma unroll
        for (int i = 0; i < 4; i++) {
            int s = i * 256 + tid;
            int m = s >> 3, kc = s & 7;
            int kg = kc ^ (m & 7);
            gl2lds16(BT + (colbase + m) * (size_t)Kd + (k0 + kg * 8), &b_lds[s * 8]);
        }
        __syncthreads();
#pragma unroll
        for (int ks = 0; ks < 2; ks++) {
            short8 af[4], bfr[4];
            int cg = ks * 4 + qd;
#pragma unroll
            for (int mt = 0; mt < 4; mt++) {
                int m = wrow + mt * 16 + cc;
                af[mt] = *(const short8*)&a_lds[(m * 8 + (cg ^ (m & 7))) * 8];
            }
#pragma unroll
            for (int nt = 0; nt < 4; nt++) {
                int n = wcol + nt * 16 + cc;
                bfr[nt] = *(const short8*)&b_lds[(n * 8 + (cg ^ (n & 7))) * 8];
            }
#pragma unroll
            for (int mt = 0; mt < 4; mt++)
#pragma unroll
                for (int nt = 0; nt < 4; nt++)
                    mfma16(acc[mt][nt], af[mt], bfr[nt]);
        }
        __syncthreads();
    }

    float sc = scale_const;
    if (scale_ptr) sc *= *scale_ptr;
#pragma unroll
    for (int mt = 0; mt < 4; mt++) {
        int g0 = (int)rowbase + wrow + mt * 16 + qd * 4;   // 4 consecutive rows
        int bq = g0 / P, rl = g0 - bq * P;
#pragma unroll
        for (int nt = 0; nt < 4; nt++) {
            int col = (int)colbase + wcol + nt * 16 + cc;
            if (col >= nq) {
#pragma unroll
                for (int r = 0; r < 4; r++)
                    Qb[(size_t)(bq * 64 + rl + r) * 512 + (col - nq)] =
                        f2bf(acc[mt][nt][r] * qscale);
            } else if (col < nsplit) {
                int idx0 = bq * Sstride + Ofs + rl;
                if (Cf) {
#pragma unroll
                    for (int r = 0; r < 4; r++)
                        Cf[(size_t)(idx0 + r) * ldc + col] = acc[mt][nt][r] * sc;
                } else {
#pragma unroll
                    for (int r = 0; r < 4; r++)
                        Ck[(size_t)(idx0 + r) * ldc + col] = f2bf(acc[mt][nt][r] * sc);
                }
            } else {
                ushort4 pk;
                pk.x = f2bf(acc[mt][nt][0] * sc);
                pk.y = f2bf(acc[mt][nt][1] * sc);
                pk.z = f2bf(acc[mt][nt][2] * sc);
                pk.w = f2bf(acc[mt][nt][3] * sc);
                *(ushort4*)&CvT[((size_t)bq * 512 + (col - nsplit)) * KVPAD + Ofs + rl] = pk;
            }
        }
    }
}

// ---------------------------------------------------------------------------
// Attention, split-kv over compacted layout. Grid (chunk=17, h=8, b=8).
// Each block covers 512 kv slots as TWO 256-slot sub-tiles with online-softmax
// rescale between them. kv slots: [0..64) latents, [64..64+cnt[b]) features.
// ---------------------------------------------------------------------------
__global__ __launch_bounds__(256) void attn_kernel(
    const unsigned short* __restrict__ Kbuf,  // [8][8448][512]
    const unsigned short* __restrict__ Vt,    // [8][512][8448]
    const unsigned short* __restrict__ Qbuf,  // [8][64][512]
    const int* __restrict__ cnt,              // [8]
    float* __restrict__ Opart,                // [1088][64][64]
    float* __restrict__ Mpart,                // [1088][64]
    float* __restrict__ Lpart)                // [1088][64]
{
    __shared__ unsigned short P_lds[64 * 264];
    __shared__ float red_max[4][64];
    __shared__ float red_sum[4][64];
    __shared__ float mrow[64];
    __shared__ float lrow[64];
    __shared__ float frow[64];

    int chunk = blockIdx.x, h = blockIdx.y, b = blockIdx.z;
    int len = 64 + cnt[b];
    int kv0 = chunk * 512;
    if (kv0 >= len) return;

    int tid = threadIdx.x, lane = tid & 63, w = tid >> 6;
    int qd = lane >> 4, cc = lane & 15;
    int pidx = (b * 8 + h) * NCHUNK + chunk;

    // Q fragments: loaded once, reused for both sub-tiles
    short8 qf[4][2];
    const unsigned short* Qb = Qbuf + ((size_t)b * 64) * 512 + h * 64;
#pragma unroll
    for (int mt = 0; mt < 4; mt++)
#pragma unroll
        for (int ks = 0; ks < 2; ks++)
            qf[mt][ks] = *(const short8*)&Qb[(size_t)(mt * 16 + cc) * 512 + ks * 32 + qd * 8];

    f32x4 acco[4];
#pragma unroll
    for (int mt = 0; mt < 4; mt++) acco[mt] = (f32x4){0.f, 0.f, 0.f, 0.f};

    const unsigned short* Kb = Kbuf + (size_t)b * KVPAD * 512 + h * 64;
    const unsigned short* Vbase = Vt + ((size_t)b * 512 + h * 64 + w * 16 + cc) * KVPAD;

#pragma unroll 1
    for (int s = 0; s < 2; s++) {
        int kvs = kv0 + s * 256;
        if (kvs >= len) break;              // uniform per block
        int kvw = kvs + w * 64;

        // ---- QK^T for this 256-kv sub-tile ----
        f32x4 acc[4][4];
#pragma unroll
        for (int mt = 0; mt < 4; mt++)
#pragma unroll
            for (int nt = 0; nt < 4; nt++)
                acc[mt][nt] = (f32x4){0.f, 0.f, 0.f, 0.f};
#pragma unroll
        for (int nt = 0; nt < 4; nt++) {
            int kvr = kvw + nt * 16 + cc;
#pragma unroll
            for (int ks = 0; ks < 2; ks++) {
                short8 kf = *(const short8*)&Kb[(size_t)kvr * 512 + ks * 32 + qd * 8];
#pragma unroll
                for (int mt = 0; mt < 4; mt++)
                    mfma16(acc[mt][nt], qf[mt][ks], kf);
            }
        }
        // mask invalid slots (>= len)
#pragma unroll
        for (int nt = 0; nt < 4; nt++) {
            int kv = kvw + nt * 16 + cc;
            if (kv >= len) {
#pragma unroll
                for (int mt = 0; mt < 4; mt++)
#pragma unroll
                    for (int r = 0; r < 4; r++) acc[mt][nt][r] = -1e30f;
            }
        }
        // ---- sub-tile max reduce ----
        float vmax[4][4];
#pragma unroll
        for (int mt = 0; mt < 4; mt++)
#pragma unroll
            for (int r = 0; r < 4; r++)
                vmax[mt][r] = fmaxf(fmaxf(acc[mt][0][r], acc[mt][1][r]),
                                    fmaxf(acc[mt][2][r], acc[mt][3][r]));
#pragma unroll
        for (int off = 1; off < 16; off <<= 1)
#pragma unroll
            for (int mt = 0; mt < 4; mt++)
#pragma unroll
                for (int r = 0; r < 4; r++)
                    vmax[mt][r] = fmaxf(vmax[mt][r], __shfl_xor(vmax[mt][r], off));
        if (cc == 0) {
#pragma unroll
            for (int mt = 0; mt < 4; mt++)
#pragma unroll
                for (int r = 0; r < 4; r++)
                    red_max[w][mt * 16 + qd * 4 + r] = vmax[mt][r];
        }
        __syncthreads();                                    // B1
        if (tid < 64) {
            float tmax = fmaxf(fmaxf(red_max[0][tid], red_max[1][tid]),
                               fmaxf(red_max[2][tid], red_max[3][tid]));
            if (s == 0) {
                mrow[tid] = tmax;
            } else {
                float mo = mrow[tid];
                float mn = fmaxf(mo, tmax);
                frow[tid] = __expf(mo - mn);
                mrow[tid] = mn;
            }
        }
        __syncthreads();                                    // B2
        // ---- P = exp(S - m), row sums ----
        float vsum[4][4];
#pragma unroll
        for (int mt = 0; mt < 4; mt++)
#pragma unroll
            for (int r = 0; r < 4; r++) {
                int row = mt * 16 + qd * 4 + r;
                float m = mrow[row];
                float ssum = 0.f;
#pragma unroll
                for (int nt = 0; nt < 4; nt++) {
                    float p = __expf(acc[mt][nt][r] - m);
                    ssum += p;
                    P_lds[row * 264 + w * 64 + nt * 16 + cc] = f2bf(p);
                }
                vsum[mt][r] = ssum;
            }
#pragma unroll
        for (int off = 1; off < 16; off <<= 1)
#pragma unroll
            for (int mt = 0; mt < 4; mt++)
#pragma unroll
                for (int r = 0; r < 4; r++)
                    vsum[mt][r] += __shfl_xor(vsum[mt][r], off);
        if (cc == 0) {
#pragma unroll
            for (int mt = 0; mt < 4; mt++)
#pragma unroll
                for (int r = 0; r < 4; r++)
                    red_sum[w][mt * 16 + qd * 4 + r] = vsum[mt][r];
        }
        __syncthreads();                                    // B3
        if (tid < 64) {
            float snew = red_sum[0][tid] + red_sum[1][tid] +
                         red_sum[2][tid] + red_sum[3][tid];
            lrow[tid] = (s == 0) ? snew : lrow[tid] * frow[tid] + snew;
        }
        // rescale accumulated O by exp(m_old - m_new) (frow stable since B2)
        if (s > 0) {
#pragma unroll
            for (int mt = 0; mt < 4; mt++)
#pragma unroll
                for (int r = 0; r < 4; r++)
                    acco[mt][r] *= frow[mt * 16 + qd * 4 + r];
        }
        // ---- PV accumulate (P_lds stable since B3; next overwrite is after
        // next iteration's B2, which all waves reach only post-PV) ----
        const unsigned short* Vb = Vbase + kvs;
#pragma unroll
        for (int ks = 0; ks < 8; ks++) {
            short8 vf = *(const short8*)&Vb[ks * 32 + qd * 8];
#pragma unroll
            for (int mt = 0; mt < 4; mt++) {
                short8 pf = *(const short8*)&P_lds[(size_t)(mt * 16 + cc) * 264 + ks * 32 + qd * 8];
                mfma16(acco[mt], pf, vf);
            }
        }
    }

    if (tid < 64) {
        Mpart[(size_t)pidx * 64 + tid] = mrow[tid];
        Lpart[(size_t)pidx * 64 + tid] = lrow[tid];
    }
    float* Ob = Opart + (size_t)pidx * 4096;
#pragma unroll
    for (int mt = 0; mt < 4; mt++)
#pragma unroll
        for (int r = 0; r < 4; r++)
            Ob[(size_t)(mt * 16 + qd * 4 + r) * 64 + w * 16 + cc] = acco[mt][r];
}

// ---------------------------------------------------------------------------
// Combine split-kv partials over ACTIVE chunks only (512-kv chunks).
// ---------------------------------------------------------------------------
__global__ __launch_bounds__(256) void combine_kernel(
    const float* __restrict__ Opart, const float* __restrict__ Mpart,
    const float* __restrict__ Lpart, const int* __restrict__ cnt,
    unsigned short* __restrict__ AttnOut)
{
    __shared__ float wls[NCHUNK][16];
    __shared__ float invl[16];
    int bh = blockIdx.x >> 2, qg = blockIdx.x & 3;
    int b = bh >> 3, h = bh & 7;
    int pbase = bh * NCHUNK;
    int nact = (64 + cnt[b] + 511) >> 9;   // active 512-kv chunks for this batch
    int tid = threadIdx.x;
    if (tid < 16) {
        int q = qg * 16 + tid;
        float M = -3.0e38f;
        for (int cn = 0; cn < nact; cn++)
            M = fmaxf(M, Mpart[(size_t)(pbase + cn) * 64 + q]);
        float l = 0.f;
        for (int cn = 0; cn < nact; cn++) {
            float wc = __expf(Mpart[(size_t)(pbase + cn) * 64 + q] - M);
            wls[cn][tid] = wc;
            l += wc * Lpart[(size_t)(pbase + cn) * 64 + q];
        }
        invl[tid] = 1.0f / l;
    }
    __syncthreads();
    int ql = tid >> 4, d4 = (tid & 15) * 4;
    int q = qg * 16 + ql;
    float ax = 0.f, ay = 0.f, az = 0.f, aw = 0.f;
    for (int cn = 0; cn < nact; cn++) {
        float wc = wls[cn][ql];
        float4 o = *(const float4*)&Opart[((size_t)(pbase + cn) * 64 + q) * 64 + d4];
        ax += wc * o.x; ay += wc * o.y; az += wc * o.z; aw += wc * o.w;
    }
    float iv = invl[ql];
    ushort4 pk;
    pk.x = f2bf(ax * iv); pk.y = f2bf(ay * iv);
    pk.z = f2bf(az * iv); pk.w = f2bf(aw * iv);
    *(ushort4*)&AttnOut[((size_t)b * 64 + q) * 512 + h * 64 + d4] = pk;
}

// ---------------------------------------------------------------------------
// Workspace layout (bytes). x_ln (0..134M) is dead after the big GEMM and is
// reused for attention partials. Qbuf/AttnOut live OUTSIDE the x_ln region.
// ---------------------------------------------------------------------------
#define OPART_OFF    ((size_t)0)            // 1088*64*64*4 = 17,825,792
#define MPART_OFF    ((size_t)34603008)     // 1088*64*4    =    278,528
#define LPART_OFF    ((size_t)35143680)
#define XLN_OFF      ((size_t)0)            // 8*8192*1024*2 = 134,217,728
#define LATLN_OFF    ((size_t)134217728)    // 512*1024*2
#define KBUF_OFF     ((size_t)135266304)    // 8*8448*512*2 = 69,206,016
#define VT_OFF       ((size_t)204472320)    // 8*512*8448*2
#define WKVQT_OFF    ((size_t)273678336)    // 1536*1024*2 = 3,145,728
#define WOUTT_OFF    ((size_t)276824064)    // 1024*512*2  = 1,048,576
#define PFX_OFF      ((size_t)277872640)    // 8*8192*4 = 262,144
#define CNT_OFF      ((size_t)278134784)    // 8*4
#define QBUF_OFF     ((size_t)278134912)    // 512*512*2 = 524,288 (outside x_ln)
#define ATTNOUT_OFF  ((size_t)278659200)    // 512*512*2 ; end 279,183,488

extern "C" void kernel_launch(void* const* d_in, const int* in_sizes, int n_in,
                              void* d_out, int out_size, void* d_ws, size_t ws_size,
                              hipStream_t stream) {
    const float* x       = (const float*)d_in[0];
    const float* latents = (const float*)d_in[1];
    const int*   mask    = (const int*)d_in[2];
    const float* kv_gate = (const float*)d_in[3];
    const float* gm      = (const float*)d_in[4];
    const float* bm      = (const float*)d_in[5];
    const float* gl      = (const float*)d_in[6];
    const float* bl      = (const float*)d_in[7];
    const float* Wq      = (const float*)d_in[8];
    const float* Wk      = (const float*)d_in[9];
    const float* Wv      = (const float*)d_in[10];
    const float* Wout    = (const float*)d_in[11];
    float* out = (float*)d_out;

    char* ws = (char*)d_ws;
    float* Opart = (float*)(ws + OPART_OFF);
    float* Mpart = (float*)(ws + MPART_OFF);
    float* Lpart = (float*)(ws + LPART_OFF);
    unsigned short* Qbuf    = (unsigned short*)(ws + QBUF_OFF);
    unsigned short* AttnOut = (unsigned short*)(ws + ATTNOUT_OFF);
    unsigned short* x_ln    = (unsigned short*)(ws + XLN_OFF);
    unsigned short* lat_ln  = (unsigned short*)(ws + LATLN_OFF);
    unsigned short* Kbuf    = (unsigned short*)(ws + KBUF_OFF);
    unsigned short* Vt      = (unsigned short*)(ws + VT_OFF);
    unsigned short* WkvqT   = (unsigned short*)(ws + WKVQT_OFF);
    unsigned short* WoutT   = (unsigned short*)(ws + WOUTT_OFF);
    int* pfx = (int*)(ws + PFX_OFF);
    int* cnt = (int*)(ws + CNT_OFF);

    // 1) Parallel mask prefix scan (one block per batch, contention-free)
    scan_kernel<<<8, 1024, 0, stream>>>(mask, pfx, cnt);

    // 2) prep: LN (compacted x via pfx + latents) + weight transposes
    prep_kernel<<<17024, 256, 0, stream>>>(
        x, latents, mask, pfx, gm, bm, gl, bl, Wk, Wv, Wq, Wout,
        x_ln, lat_ln, WkvqT, WoutT);

    // 3) Latent K/V/Q (K,V x kv_gate -> slots 0..63; Q x 0.125) — small GEMM
    gemm_bf16<<<dim3(12, 4), 256, 0, stream>>>(
        lat_ln, WkvqT, 1024, Kbuf, nullptr, Vt, Qbuf,
        512, 1024, 512, 64, KVPAD, 0, 1.0f, 0.125f, kv_gate, nullptr);

    // 4) Big KV projection (compacted rows): 256^2 8-phase counted-vmcnt GEMM
    gemm256<<<dim3(4, 256), 512, 0, stream>>>(x_ln, WkvqT, Kbuf, Vt, cnt);

    // 5) Split-kv attention partials (512-kv chunks, 2 sub-tiles per block)
    attn_kernel<<<dim3(NCHUNK, 8, 8), 256, 0, stream>>>(
        Kbuf, Vt, Qbuf, cnt, Opart, Mpart, Lpart);

    // 6) Combine partials -> AttnOut bf16 [512][512]
    combine_kernel<<<256, 256, 0, stream>>>(Opart, Mpart, Lpart, cnt, AttnOut);

    // 7) Output projection: AttnOut(512x512) @ Wout -> out fp32 (8,64,1024)
    gemm_bf16<<<dim3(8, 4), 256, 0, stream>>>(
        AttnOut, WoutT, 512, nullptr, out, nullptr, nullptr,
        1 << 30, 1 << 30, 1024, 64, 64, 0, 1.0f, 0.f, nullptr, nullptr);
}